// Round 3
// baseline (303.455 us; speedup 1.0000x reference)
//
#include <hip/hip_runtime.h>
#include <hip/hip_bf16.h>

#define BATCH 32
#define CIN   256
#define COUT  256
#define Hd    56
#define Wd    56
#define HW    (Hd*Wd)

typedef __attribute__((ext_vector_type(8))) short bf16x8;
typedef __attribute__((ext_vector_type(4))) float f32x4;

typedef const __attribute__((address_space(1))) void* gas1_t;
typedef __attribute__((address_space(3))) void* las3_t;

__device__ __forceinline__ unsigned short f2bf_rne(float f) {
    unsigned u = __builtin_bit_cast(unsigned, f);
    u += 0x7fffu + ((u >> 16) & 1u);
    return (unsigned short)(u >> 16);
}

// ---------------------------------------------------------------------------
// Weight prep: Wc[np][kp] center taps, Wg[np][t][j] off-center taps, bsum[np].
// permutation: np = (n%4)*64 + n/4 ; kp likewise for inputs.
// ---------------------------------------------------------------------------
__global__ void hetconv_prep(const float* __restrict__ W, const float* __restrict__ b,
                             unsigned short* __restrict__ Wc,
                             unsigned short* __restrict__ Wg,
                             float* __restrict__ bsum) {
    const int np = blockIdx.x;
    const int lane = threadIdx.x;
    const int r = np >> 6;
    const int n = ((np & 63) << 2) | r;

    float s = 0.f;
    for (int i = lane; i < CIN; i += 64) s += b[n * CIN + i];
    #pragma unroll
    for (int off = 32; off > 0; off >>= 1) s += __shfl_down(s, off, 64);
    if (lane == 0) bsum[np] = s;

    for (int kp = lane; kp < CIN; kp += 64) {
        int i = ((kp & 63) << 2) | (kp >> 6);
        Wc[np * CIN + kp] = f2bf_rne(W[(n * CIN + i) * 9 + 4]);
    }
    for (int u = lane; u < 8 * 64; u += 64) {
        int t = u >> 6, j = u & 63;
        int tap = t + (t >= 4);
        int i = (j << 2) | r;
        Wg[np * 512 + u] = f2bf_rne(W[(n * CIN + i) * 9 + tap]);
    }
}

// ---------------------------------------------------------------------------
// x convert: xb[b][pass2][row 58 (rows 0,57 zero pad)][col 64 (56-63 zero)]
// [128 ch bf16, octet-XOR-swizzled by col&7].
// ---------------------------------------------------------------------------
__global__ __launch_bounds__(512) void hetconv_xconv(const float* __restrict__ x,
                                                     unsigned short* __restrict__ xb) {
    const int bid = blockIdx.x;
    const int b  = bid / 58;
    const int pr = bid % 58;
    const int tid = threadIdx.x;
    const int col = tid & 63;
    const int wid = tid >> 6;
    const int grow = pr - 1;
    const bool ok = (grow >= 0) && (grow < Hd) && (col < Wd);
    const float* xp = x + (size_t)b * CIN * HW + (size_t)grow * Wd + col;

    #pragma unroll
    for (int rd = 0; rd < 4; ++rd) {
        int octG = rd * 8 + wid;
        int pass = octG >> 4;
        int g    = octG & 15;
        bf16x8 pk;
        #pragma unroll
        for (int e = 0; e < 8; ++e) {
            int kp = pass * 128 + g * 8 + e;
            int ic = ((kp & 63) << 2) | (kp >> 6);
            float f = ok ? xp[(size_t)ic * HW] : 0.f;
            pk[e] = (short)f2bf_rne(f);
        }
        size_t dst = ((size_t)(b * 2 + pass) * 58 + pr) * 8192
                   + col * 128 + ((g ^ (col & 7)) * 8);
        *reinterpret_cast<bf16x8*>(xb + dst) = pk;
    }
}

// ---------------------------------------------------------------------------
// Staging: one 64 KB slab (4 padded rows x 64 cols x 128 ch) -> LDS buffer.
// ---------------------------------------------------------------------------
__device__ __forceinline__ void stage_slab(const unsigned short* __restrict__ xb,
                                           unsigned short* lds_dst,
                                           int b, int tr, int p, int wid, int lane) {
    const unsigned short* slab = xb + ((size_t)((b * 2 + p) * 58 + tr)) * 8192;
    #pragma unroll
    for (int rd = 0; rd < 8; ++rd) {
        int vbase = rd * 512 + wid * 64;           // 16B units, wave-uniform
        __builtin_amdgcn_global_load_lds(
            (gas1_t)(slab + (size_t)(vbase + lane) * 8),
            (las3_t)(lds_dst + vbase * 8), 16, 0, 0);
    }
}

// ---------------------------------------------------------------------------
// Compute one 128-channel pass from an LDS buffer (verified R2 structure).
// ---------------------------------------------------------------------------
__device__ __forceinline__ void compute_pass(const unsigned short* xsb,
                                             const unsigned short* __restrict__ Wc,
                                             const unsigned short* __restrict__ Wg,
                                             int p, int h, int r, int l15, int l4,
                                             f32x4 (&acc)[4][4]) {
    // dense center-tap GEMM: 4 K-steps of 32 channels
    {
        const int srow = (h + 1) * 64;
        #pragma unroll
        for (int ks = 0; ks < 4; ++ks) {
            bf16x8 a[4];
            #pragma unroll
            for (int mf = 0; mf < 4; ++mf) {
                int m = r * 64 + mf * 16 + l15;
                a[mf] = *reinterpret_cast<const bf16x8*>(
                    Wc + (size_t)m * 256 + p * 128 + ks * 32 + l4 * 8);
            }
            #pragma unroll
            for (int nf = 0; nf < 4; ++nf) {
                int s = srow + nf * 16 + l15;
                int o = ks * 4 + l4;
                int addr = s * 256 + ((o ^ (s & 7)) << 4);
                bf16x8 bb = *reinterpret_cast<const bf16x8*>(
                    reinterpret_cast<const char*>(xsb) + addr);
                #pragma unroll
                for (int mf = 0; mf < 4; ++mf)
                    acc[mf][nf] = __builtin_amdgcn_mfma_f32_16x16x32_bf16(
                        a[mf], bb, acc[mf][nf], 0, 0, 0);
            }
        }
    }
    // grouped off-center taps (this wave's residue channels)
    if ((r >> 1) == p) {
        const int cbase = (r & 1) * 64;
        #pragma unroll
        for (int t = 0; t < 8; ++t) {
            const int tap = t + (t >= 4);
            const int dy = tap / 3 - 1;
            const int dx = tap % 3 - 1;
            const int srow = (h + 1 + dy) * 64;
            #pragma unroll
            for (int ks2 = 0; ks2 < 2; ++ks2) {
                bf16x8 a[4];
                #pragma unroll
                for (int mf = 0; mf < 4; ++mf) {
                    int m = r * 64 + mf * 16 + l15;
                    a[mf] = *reinterpret_cast<const bf16x8*>(
                        Wg + ((size_t)m * 8 + t) * 64 + ks2 * 32 + l4 * 8);
                }
                #pragma unroll
                for (int nf = 0; nf < 4; ++nf) {
                    int c2 = nf * 16 + l15 + dx;
                    c2 = ((unsigned)c2 < 64u) ? c2 : 56;   // col 56 is zero pad
                    int s = srow + c2;
                    int o = ((cbase + ks2 * 32) >> 3) + l4;
                    int addr = s * 256 + ((o ^ (s & 7)) << 4);
                    bf16x8 bb = *reinterpret_cast<const bf16x8*>(
                        reinterpret_cast<const char*>(xsb) + addr);
                    #pragma unroll
                    for (int mf = 0; mf < 4; ++mf)
                        acc[mf][nf] = __builtin_amdgcn_mfma_f32_16x16x32_bf16(
                            a[mf], bb, acc[mf][nf], 0, 0, 0);
                }
            }
        }
    }
}

// ---------------------------------------------------------------------------
// Main: 256 persistent blocks = 32 b x 8 rowgroups (4,4,4,4,3,3,3,3 tiles).
// Per tile: 2 passes; per step: issue next-slab prefetch, compute current,
// vmcnt(0) + s_barrier (single barrier per step, prefetch hidden under MFMA).
// ---------------------------------------------------------------------------
__global__ __launch_bounds__(512, 2) void hetconv_main(const unsigned short* __restrict__ xb,
                             const unsigned short* __restrict__ Wc,
                             const unsigned short* __restrict__ Wg,
                             const float* __restrict__ bsum,
                             float* __restrict__ y) {
    __shared__ unsigned short xs[2][4 * 64 * 128];   // 2 x 64 KB

    const int bid = blockIdx.x;
    const int b   = bid >> 3;
    const int rg  = bid & 7;
    const int tr0 = (rg < 4) ? rg * 8 : 32 + (rg - 4) * 6;   // first output row
    const int T   = (rg < 4) ? 4 : 3;                        // 2-row tiles

    const int tid  = threadIdx.x;
    const int lane = tid & 63;
    const int wid  = tid >> 6;
    const int h = wid & 1;
    const int r = wid >> 1;
    const int l15 = lane & 15;
    const int l4  = lane >> 4;

    float bias[4][4];
    #pragma unroll
    for (int mf = 0; mf < 4; ++mf)
        #pragma unroll
        for (int j = 0; j < 4; ++j)
            bias[mf][j] = bsum[r * 64 + mf * 16 + l4 * 4 + j];

    f32x4 acc[4][4];
    #pragma unroll
    for (int i = 0; i < 4; ++i)
        #pragma unroll
        for (int j = 0; j < 4; ++j) acc[i][j] = f32x4{0.f, 0.f, 0.f, 0.f};

    // prologue: stage (tile0, pass0) and drain once
    stage_slab(xb, xs[0], b, tr0, 0, wid, lane);
    asm volatile("s_waitcnt vmcnt(0)" ::: "memory");
    __builtin_amdgcn_s_barrier();

    for (int t = 0; t < T; ++t) {
        const int tr = tr0 + t * 2;

        // ---- step (t, pass 0): prefetch (t,1), compute pass 0 ----
        stage_slab(xb, xs[1], b, tr, 1, wid, lane);
        compute_pass(xs[0], Wc, Wg, 0, h, r, l15, l4, acc);
        asm volatile("s_waitcnt vmcnt(0)" ::: "memory");
        __builtin_amdgcn_s_barrier();

        // ---- step (t, pass 1): prefetch (t+1,0), compute pass 1 ----
        if (t + 1 < T) stage_slab(xb, xs[0], b, tr + 2, 0, wid, lane);
        compute_pass(xs[1], Wc, Wg, 1, h, r, l15, l4, acc);

        // ---- epilogue for this tile: bias + direct stores, rezero acc ----
        #pragma unroll
        for (int mf = 0; mf < 4; ++mf) {
            #pragma unroll
            for (int nf = 0; nf < 4; ++nf) {
                int col = nf * 16 + l15;
                #pragma unroll
                for (int j = 0; j < 4; ++j) {
                    if (col < Wd) {
                        int np = r * 64 + mf * 16 + l4 * 4 + j;
                        int n  = ((np & 63) << 2) | r;
                        y[(((size_t)b * COUT + n) * Hd + (tr + h)) * Wd + col]
                            = acc[mf][nf][j] + bias[mf][j];
                    }
                }
                acc[mf][nf] = f32x4{0.f, 0.f, 0.f, 0.f};
            }
        }

        asm volatile("s_waitcnt vmcnt(0)" ::: "memory");
        __builtin_amdgcn_s_barrier();
    }
}

extern "C" void kernel_launch(void* const* d_in, const int* in_sizes, int n_in,
                              void* d_out, int out_size, void* d_ws, size_t ws_size,
                              hipStream_t stream) {
    const float* x = (const float*)d_in[0];
    const float* W = (const float*)d_in[1];
    const float* b = (const float*)d_in[2];
    float* y = (float*)d_out;

    unsigned short* Wc   = (unsigned short*)d_ws;                        // 131072 B
    unsigned short* Wg   = (unsigned short*)((char*)d_ws + 131072);      // 262144 B
    float*          bsum = (float*)((char*)d_ws + 393216);               // 1024 B
    unsigned short* xb   = (unsigned short*)((char*)d_ws + 394240);      // 60,817,408 B

    hipLaunchKernelGGL(hetconv_prep,  dim3(256),        dim3(64),  0, stream, W, b, Wc, Wg, bsum);
    hipLaunchKernelGGL(hetconv_xconv, dim3(BATCH * 58), dim3(512), 0, stream, x, xb);
    hipLaunchKernelGGL(hetconv_main,  dim3(256),        dim3(512), 0, stream, xb, Wc, Wg, bsum, y);
}